// Round 14
// baseline (450.291 us; speedup 1.0000x reference)
//
#include <hip/hip_runtime.h>
#include <math.h>

constexpr int NB = 2, NN = 2048, NC = 256, NL = 4, NH = 4, ND = 64;
constexpr float EPSV = 1e-5f;

using half8 = __attribute__((ext_vector_type(8))) _Float16;
using half4 = __attribute__((ext_vector_type(4))) _Float16;
using f32x4 = __attribute__((ext_vector_type(4))) float;

__device__ __forceinline__ f32x4 mfma16(half8 a, half8 b, f32x4 c) {
    return __builtin_amdgcn_mfma_f32_16x16x32_f16(a, b, c, 0, 0, 0);
}
__device__ __forceinline__ half8 cvt8(const float* p) {
    float4 x0 = *(const float4*)p, x1 = *(const float4*)(p + 4);
    half8 h;
    h[0]=(_Float16)x0.x; h[1]=(_Float16)x0.y; h[2]=(_Float16)x0.z; h[3]=(_Float16)x0.w;
    h[4]=(_Float16)x1.x; h[5]=(_Float16)x1.y; h[6]=(_Float16)x1.z; h[7]=(_Float16)x1.w;
    return h;
}

// ---------------------------------------------------------------------------
// out[b][n][o] = epi( sum_k W[o][k] * in[b][n][k] ), K=NC. (validated R7-R13)
template<int EPI, bool INF16, bool OUT32>
__global__ __launch_bounds__(256) void gemm_mfma(
    const float* __restrict__ Wg, const float* __restrict__ bias,
    const float* __restrict__ gam, const float* __restrict__ bet,
    const void* __restrict__ inp, void* __restrict__ outp)
{
    int b = blockIdx.x, o0 = blockIdx.y * 64, n0 = blockIdx.z * 32;
    int t = threadIdx.x, w = t >> 6, li = t & 15, qd = (t >> 4) & 3;
    const float* wr = Wg + (size_t)(o0 + w * 16 + li) * NC + qd * 8;
    half8 af[8];
#pragma unroll
    for (int ks = 0; ks < 8; ++ks) af[ks] = cvt8(wr + ks * 32);
    f32x4 acc[2];
    acc[0] = {0.f, 0.f, 0.f, 0.f}; acc[1] = {0.f, 0.f, 0.f, 0.f};
#pragma unroll
    for (int ks = 0; ks < 8; ++ks) {
#pragma unroll
        for (int g = 0; g < 2; ++g) {
            int n = n0 + g * 16 + li;
            half8 bf;
            if (INF16) {
                bf = *(const half8*)((const _Float16*)inp +
                        ((size_t)(b * NN + n) * NC + ks * 32 + qd * 8));
            } else {
                bf = cvt8((const float*)inp + ((size_t)(b * NN + n) * NC + ks * 32 + qd * 8));
            }
            acc[g] = mfma16(af[ks], bf, acc[g]);
        }
    }
    int ob = o0 + w * 16 + qd * 4;
    float4 bs = *(const float4*)(bias + ob);
    float4 gs = {0,0,0,0}, be = {0,0,0,0};
    if (EPI == 1) { gs = *(const float4*)(gam + ob); be = *(const float4*)(bet + ob); }
    float scl = rsqrtf(1.f + EPSV);
#pragma unroll
    for (int g = 0; g < 2; ++g) {
        int n = n0 + g * 16 + li;
        float v4[4];
#pragma unroll
        for (int r = 0; r < 4; ++r) {
            float v = acc[g][r] + ((const float*)&bs)[r];
            if (EPI == 1)
                v = fmaxf(0.f, v * (((const float*)&gs)[r] * scl) + ((const float*)&be)[r]);
            v4[r] = v;
        }
        if (OUT32) {
            float4 fv = {v4[0], v4[1], v4[2], v4[3]};
            *(float4*)((float*)outp + (size_t)(b * NN + n) * NC + ob) = fv;
        } else {
            half4 hv;
#pragma unroll
            for (int r = 0; r < 4; ++r) hv[r] = (_Float16)v4[r];
            *(half4*)((_Float16*)outp + (size_t)(b * NN + n) * NC + ob) = hv;
        }
    }
}

// q/k -> [bh][n][64] ; v -> [bh][64][n] (+bias). grid (8, NN/64). (validated R8/R10)
__global__ __launch_bounds__(256) void qkv_fused(
    const float* __restrict__ qw, const float* __restrict__ kw,
    const float* __restrict__ vw, const float* __restrict__ vb,
    const _Float16* __restrict__ h16, _Float16* __restrict__ q16,
    _Float16* __restrict__ k16, _Float16* __restrict__ v16, int l)
{
    int bh = blockIdx.x, n0 = blockIdx.y * 64;
    int hh = bh & 3, b = bh >> 2;
    size_t wbase = (size_t)(l * NH + hh) * ND * ND;
    int t = threadIdx.x, w = t >> 6, li = t & 15, qd = (t >> 4) & 3;
    size_t wro = (size_t)(w * 16 + li) * ND + qd * 8;
    half8 aq0 = cvt8(qw + wbase + wro), aq1 = cvt8(qw + wbase + wro + 32);
    half8 ak0 = cvt8(kw + wbase + wro), ak1 = cvt8(kw + wbase + wro + 32);
    half8 av0 = cvt8(vw + wbase + wro), av1 = cvt8(vw + wbase + wro + 32);
    f32x4 accq[4], acck[4], accv[4];
#pragma unroll
    for (int g = 0; g < 4; ++g) {
        accq[g] = {0.f,0.f,0.f,0.f}; acck[g] = {0.f,0.f,0.f,0.f}; accv[g] = {0.f,0.f,0.f,0.f};
    }
#pragma unroll
    for (int g = 0; g < 4; ++g) {
        int n = n0 + g * 16 + li;
        const _Float16* hb = h16 + ((size_t)(b * NN + n) * NC + hh * 64 + qd * 8);
        half8 b0 = *(const half8*)(hb);
        half8 b1 = *(const half8*)(hb + 32);
        accq[g] = mfma16(aq0, b0, accq[g]); accq[g] = mfma16(aq1, b1, accq[g]);
        acck[g] = mfma16(ak0, b0, acck[g]); acck[g] = mfma16(ak1, b1, acck[g]);
        accv[g] = mfma16(av0, b0, accv[g]); accv[g] = mfma16(av1, b1, accv[g]);
    }
    int ob = w * 16 + qd * 4;
    _Float16* qo = q16 + (size_t)bh * NN * ND;
    _Float16* ko = k16 + (size_t)bh * NN * ND;
#pragma unroll
    for (int g = 0; g < 4; ++g) {
        int n = n0 + g * 16 + li;
        half4 hq, hk;
#pragma unroll
        for (int r = 0; r < 4; ++r) { hq[r] = (_Float16)accq[g][r]; hk[r] = (_Float16)acck[g][r]; }
        *(half4*)(qo + (size_t)n * ND + ob) = hq;
        *(half4*)(ko + (size_t)n * ND + ob) = hk;
    }
    float4 vb4 = *(const float4*)(vb + (size_t)(l * NH + hh) * ND + ob);
    _Float16* vo = v16 + (size_t)bh * ND * NN;
#pragma unroll
    for (int g = 0; g < 4; ++g) {
        int n = n0 + g * 16 + li;
#pragma unroll
        for (int r = 0; r < 4; ++r)
            vo[(size_t)(ob + r) * NN + n] = (_Float16)(accv[g][r] + ((const float*)&vb4)[r]);
    }
}

// rowsum partials: rowsum_p[ms][bh][n] = sum_{m in ms-range} exp(S[n,m]).
// grid (8, NN/64, 4), block 256; m-tile 128/iter (4 iters, 16 MFMA each).
__global__ __launch_bounds__(256) void rowsum_part(
    const _Float16* __restrict__ qh, const _Float16* __restrict__ kh,
    float* __restrict__ rowsum_p)
{
    int bh = blockIdx.x, nt = blockIdx.y, ms = blockIdx.z;
    const _Float16* qp = qh + (size_t)bh * NN * ND;
    const _Float16* kp = kh + (size_t)bh * NN * ND;
    int t = threadIdx.x, w = t >> 6, li = t & 15, qd = (t >> 4) & 3;
    int nr = nt * 64 + w * 16;
    half8 aq0 = *(const half8*)(qp + (size_t)(nr + li) * ND + qd * 8);
    half8 aq1 = *(const half8*)(qp + (size_t)(nr + li) * ND + qd * 8 + 32);
    float rsacc[4] = {0.f, 0.f, 0.f, 0.f};
    for (int it = 0; it < 4; ++it) {
        int m0 = ms * 512 + it * 128;
        f32x4 s[8];
#pragma unroll
        for (int g = 0; g < 8; ++g) {
            const _Float16* kb = kp + (size_t)(m0 + g * 16 + li) * ND + qd * 8;
            half8 b0 = *(const half8*)(kb);
            half8 b1 = *(const half8*)(kb + 32);
            s[g] = {0.f, 0.f, 0.f, 0.f};
            s[g] = mfma16(aq0, b0, s[g]);
            s[g] = mfma16(aq1, b1, s[g]);
        }
#pragma unroll
        for (int r = 0; r < 4; ++r) {
            float e = 0.f;
#pragma unroll
            for (int g = 0; g < 8; ++g) e += __expf(s[g][r]);
            rsacc[r] += e;
        }
    }
#pragma unroll
    for (int r = 0; r < 4; ++r) {
        float v = rsacc[r];
        v += __shfl_xor(v, 1); v += __shfl_xor(v, 2);
        v += __shfl_xor(v, 4); v += __shfl_xor(v, 8);
        if (li == 0) rowsum_p[((size_t)(ms * NB * NH + bh)) * NN + nr + qd * 4 + r] = v;
    }
}

// attn partials: per (bh, m-tile 64, ns of 4): n-range 512, n-tile 128/iter
// (4 iters, 4 barriers). Two q-halves per iter (2 indep S chains); PV K=128.
// fp16 xr partials. grid (8, 32, 4), block 256.
__global__ __launch_bounds__(256) void attn_part(
    const _Float16* __restrict__ qh, const _Float16* __restrict__ kh,
    const _Float16* __restrict__ vh, const float* __restrict__ rowsum_p,
    _Float16* __restrict__ xrp16, float* __restrict__ csp)
{
    int bh = blockIdx.x, m0 = blockIdx.y * 64, ns = blockIdx.z;
    const _Float16* qp = qh + (size_t)bh * NN * ND;
    const _Float16* kp = kh + (size_t)bh * NN * ND;
    const _Float16* vp = vh + (size_t)bh * ND * NN;
    __shared__ __align__(16) _Float16 Plds[2][64 * 136];   // [m][n_local 0..127]
    __shared__ float cs_wave[4][64];
    int t = threadIdx.x, w = t >> 6, li = t & 15, qd = (t >> 4) & 3;
    const size_t RSS = (size_t)NB * NH * NN;
    half8 bk[4][2];
#pragma unroll
    for (int g = 0; g < 4; ++g) {
        const _Float16* kb = kp + (size_t)(m0 + g * 16 + li) * ND + qd * 8;
        bk[g][0] = *(const half8*)(kb);
        bk[g][1] = *(const half8*)(kb + 32);
    }
    f32x4 acc[4];
#pragma unroll
    for (int g = 0; g < 4; ++g) acc[g] = {0.f, 0.f, 0.f, 0.f};
    float csacc[4] = {0.f, 0.f, 0.f, 0.f};
    // q base for this wave (half A = +0 rows, half B = +64 rows, iter step 128 rows)
    const _Float16* qbase = qp + (size_t)(ns * 512 + w * 16 + li) * ND + qd * 8;
    half8 aqA0 = *(const half8*)(qbase);
    half8 aqA1 = *(const half8*)(qbase + 32);
    half8 aqB0 = *(const half8*)(qbase + (size_t)64 * ND);
    half8 aqB1 = *(const half8*)(qbase + (size_t)64 * ND + 32);
    for (int it = 0; it < 4; ++it) {
        int n0 = ns * 512 + it * 128;
        _Float16* Pb = Plds[it & 1];
        // v prefetch (4 K-slices of 32 n each), consumed after the barrier
        const _Float16* vrow = vp + (size_t)(w * 16 + li) * NN + n0 + qd * 8;
        half8 av0 = *(const half8*)(vrow);
        half8 av1 = *(const half8*)(vrow + 32);
        half8 av2 = *(const half8*)(vrow + 64);
        half8 av3 = *(const half8*)(vrow + 96);
        // ---- half A: S, normalize, store ----
        {
            f32x4 s[4];
#pragma unroll
            for (int g = 0; g < 4; ++g) {
                s[g] = {0.f, 0.f, 0.f, 0.f};
                s[g] = mfma16(aqA0, bk[g][0], s[g]);
                s[g] = mfma16(aqA1, bk[g][1], s[g]);
            }
            int ri = bh * NN + n0 + w * 16 + qd * 4;
            float4 r0 = *(const float4*)(rowsum_p + ri);
            float4 r1 = *(const float4*)(rowsum_p + RSS + ri);
            float4 r2 = *(const float4*)(rowsum_p + 2 * RSS + ri);
            float4 r3 = *(const float4*)(rowsum_p + 3 * RSS + ri);
            float irs[4];
            irs[0] = 1.f / (r0.x + r1.x + r2.x + r3.x);
            irs[1] = 1.f / (r0.y + r1.y + r2.y + r3.y);
            irs[2] = 1.f / (r0.z + r1.z + r2.z + r3.z);
            irs[3] = 1.f / (r0.w + r1.w + r2.w + r3.w);
#pragma unroll
            for (int g = 0; g < 4; ++g) {
                half4 pv; float lsum = 0.f;
#pragma unroll
                for (int r = 0; r < 4; ++r) {
                    float p = __expf(s[g][r]) * irs[r];
                    lsum += p;
                    pv[r] = (_Float16)p;
                }
                csacc[g] += lsum;
                *(half4*)(&Pb[(g * 16 + li) * 136 + w * 16 + qd * 4]) = pv;
            }
        }
        // ---- half B: S, normalize, store at +64 ----
        {
            f32x4 s[4];
#pragma unroll
            for (int g = 0; g < 4; ++g) {
                s[g] = {0.f, 0.f, 0.f, 0.f};
                s[g] = mfma16(aqB0, bk[g][0], s[g]);
                s[g] = mfma16(aqB1, bk[g][1], s[g]);
            }
            int ri = bh * NN + n0 + 64 + w * 16 + qd * 4;
            float4 r0 = *(const float4*)(rowsum_p + ri);
            float4 r1 = *(const float4*)(rowsum_p + RSS + ri);
            float4 r2 = *(const float4*)(rowsum_p + 2 * RSS + ri);
            float4 r3 = *(const float4*)(rowsum_p + 3 * RSS + ri);
            float irs[4];
            irs[0] = 1.f / (r0.x + r1.x + r2.x + r3.x);
            irs[1] = 1.f / (r0.y + r1.y + r2.y + r3.y);
            irs[2] = 1.f / (r0.z + r1.z + r2.z + r3.z);
            irs[3] = 1.f / (r0.w + r1.w + r2.w + r3.w);
#pragma unroll
            for (int g = 0; g < 4; ++g) {
                half4 pv; float lsum = 0.f;
#pragma unroll
                for (int r = 0; r < 4; ++r) {
                    float p = __expf(s[g][r]) * irs[r];
                    lsum += p;
                    pv[r] = (_Float16)p;
                }
                csacc[g] += lsum;
                *(half4*)(&Pb[(g * 16 + li) * 136 + 64 + w * 16 + qd * 4]) = pv;
            }
        }
        // prefetch next iteration's q halves before the barrier drain
        if (it < 3) {
            const _Float16* qn = qbase + (size_t)(it + 1) * 128 * ND;
            aqA0 = *(const half8*)(qn);
            aqA1 = *(const half8*)(qn + 32);
            aqB0 = *(const half8*)(qn + (size_t)64 * ND);
            aqB1 = *(const half8*)(qn + (size_t)64 * ND + 32);
        }
        __syncthreads();   // P_i visible; double buffer protects P_{i-1} readers
        // ---- PV: K=128 over 4 slices ----
#pragma unroll
        for (int g = 0; g < 4; ++g) {
            const _Float16* pr = &Pb[(g * 16 + li) * 136 + qd * 8];
            half8 b0 = *(const half8*)(pr);
            half8 b1 = *(const half8*)(pr + 32);
            half8 b2 = *(const half8*)(pr + 64);
            half8 b3 = *(const half8*)(pr + 96);
            acc[g] = mfma16(av0, b0, acc[g]);
            acc[g] = mfma16(av1, b1, acc[g]);
            acc[g] = mfma16(av2, b2, acc[g]);
            acc[g] = mfma16(av3, b3, acc[g]);
        }
    }
#pragma unroll
    for (int g = 0; g < 4; ++g) {
        float v = csacc[g];
        v += __shfl_xor(v, 16); v += __shfl_xor(v, 32);
        if (qd == 0) cs_wave[w][g * 16 + li] = v;
    }
    __syncthreads();
    if (t < 64) {
        float cs = cs_wave[0][t] + cs_wave[1][t] + cs_wave[2][t] + cs_wave[3][t];
        csp[((size_t)ns * NB * NH + bh) * NN + m0 + t] = cs;
    }
    _Float16* xo = xrp16 + (size_t)ns * ((size_t)NB * NC * NN);
#pragma unroll
    for (int g = 0; g < 4; ++g)
#pragma unroll
        for (int r = 0; r < 4; ++r)
            xo[(size_t)(bh * 64 + w * 16 + qd * 4 + r) * NN + m0 + g * 16 + li] =
                (_Float16)acc[g][r];
}

// d16[b][n][c] = h16 - (sum_ns xr_ns)[c][n] / (1e-9 + sum_ns cs_ns[n])
// grid (8, NN/32, 2). (validated R10)
__global__ __launch_bounds__(256) void reduce_dx(
    const _Float16* __restrict__ xrp16, const float* __restrict__ csp,
    const _Float16* __restrict__ h16, _Float16* __restrict__ d16)
{
    int bh = blockIdx.x, n0 = blockIdx.y * 32, c0g = blockIdx.z * 32;
    int b = bh >> 2, cbase = (bh & 3) * 64 + c0g;
    __shared__ float ts[32][33];
    int t = threadIdx.x, xcol = t & 31, yr = t >> 5;
    int m = n0 + xcol;
    const size_t CSS = (size_t)NB * NH * NN;
    float cs = 1e-9f + csp[(size_t)bh * NN + m] + csp[CSS + bh * NN + m]
             + csp[2 * CSS + bh * NN + m] + csp[3 * CSS + bh * NN + m];
    float icv = 1.f / cs;
    const size_t XSS = (size_t)NB * NC * NN;
#pragma unroll
    for (int r = 0; r < 4; ++r) {
        int c = yr + 8 * r;
        size_t off = (size_t)(bh * 64 + c0g + c) * NN + m;
        float s = (float)xrp16[off] + (float)xrp16[XSS + off]
                + (float)xrp16[2 * XSS + off] + (float)xrp16[3 * XSS + off];
        ts[c][xcol] = s * icv;
    }
    __syncthreads();
#pragma unroll
    for (int r = 0; r < 4; ++r) {
        int n = n0 + yr + 8 * r;
        size_t off = (size_t)(b * NN + n) * NC + cbase + xcol;
        d16[off] = (_Float16)((float)h16[off] - ts[xcol][yr + 8 * r]);
    }
}

// t = Wt d + tb ; hn = h + relu(bn(t)).  grid (8, NN/32) (validated R7-R13)
__global__ __launch_bounds__(256) void delta_mfma(
    const float* __restrict__ tw, const float* __restrict__ tb,
    const float* __restrict__ bng, const float* __restrict__ bnb,
    const _Float16* __restrict__ h16, const _Float16* __restrict__ d16,
    _Float16* __restrict__ hn16, int l)
{
    int bh = blockIdx.x, n0 = blockIdx.y * 32;
    int hh = bh & 3, b = bh >> 2;
    const float* wp = tw + (size_t)(l * NH + hh) * ND * ND;
    int t = threadIdx.x, w = t >> 6, li = t & 15, qd = (t >> 4) & 3;
    const float* wr = wp + (size_t)(w * 16 + li) * ND + qd * 8;
    half8 af0 = cvt8(wr), af1 = cvt8(wr + 32);
    f32x4 acc[2];
    acc[0] = {0.f, 0.f, 0.f, 0.f}; acc[1] = {0.f, 0.f, 0.f, 0.f};
#pragma unroll
    for (int g = 0; g < 2; ++g) {
        int n = n0 + g * 16 + li;
        const _Float16* db = d16 + ((size_t)(b * NN + n) * NC + hh * 64 + qd * 8);
        half8 b0 = *(const half8*)(db);
        half8 b1 = *(const half8*)(db + 32);
        acc[g] = mfma16(af0, b0, acc[g]);
        acc[g] = mfma16(af1, b1, acc[g]);
    }
    int ob = w * 16 + qd * 4;
    float4 tb4 = *(const float4*)(tb  + (size_t)(l * NH + hh) * ND + ob);
    float4 g4  = *(const float4*)(bng + (size_t)(l * NH + hh) * ND + ob);
    float4 b4  = *(const float4*)(bnb + (size_t)(l * NH + hh) * ND + ob);
    float scl = rsqrtf(1.f + EPSV);
#pragma unroll
    for (int g = 0; g < 2; ++g) {
        int n = n0 + g * 16 + li;
        size_t off = (size_t)(b * NN + n) * NC + hh * 64 + ob;
        half4 h4 = *(const half4*)(h16 + off);
        half4 hv;
#pragma unroll
        for (int r = 0; r < 4; ++r) {
            float tv = acc[g][r] + ((const float*)&tb4)[r];
            float x2 = fmaxf(0.f, tv * (((const float*)&g4)[r] * scl) + ((const float*)&b4)[r]);
            hv[r] = (_Float16)((float)h4[r] + x2);
        }
        *(half4*)(hn16 + off) = hv;
    }
}

extern "C" void kernel_launch(void* const* d_in, const int* in_sizes, int n_in,
                              void* d_out, int out_size, void* d_ws, size_t ws_size,
                              hipStream_t stream)
{
    (void)in_sizes; (void)n_in; (void)out_size; (void)ws_size;
    const float* x      = (const float*)d_in[0];
    const float* in_w1  = (const float*)d_in[1];
    const float* in_b1  = (const float*)d_in[2];
    const float* in_g1  = (const float*)d_in[3];
    const float* in_be1 = (const float*)d_in[4];
    const float* in_w2  = (const float*)d_in[5];
    const float* in_b2  = (const float*)d_in[6];
    const float* in_g2  = (const float*)d_in[7];
    const float* in_be2 = (const float*)d_in[8];
    const float* q_w    = (const float*)d_in[9];
    const float* k_w    = (const float*)d_in[10];
    const float* v_w    = (const float*)d_in[11];
    const float* v_b    = (const float*)d_in[12];
    const float* t_w    = (const float*)d_in[13];
    const float* t_b    = (const float*)d_in[14];
    const float* bn_g   = (const float*)d_in[15];
    const float* bn_b   = (const float*)d_in[16];
    const float* proj_w = (const float*)d_in[17];
    const float* proj_b = (const float*)d_in[18];

    float* ws = (float*)d_ws;
    const size_t M = (size_t)NB * NC * NN;             // 1,048,576
    float* rowsum_p = ws;                              // 4 x 16384 fp32
    float* csp      = ws + 65536;                      // 4 x 16384 fp32
    _Float16* xrp16 = (_Float16*)(ws + 131072);        // 4 x M halfs
    _Float16* hbase = (_Float16*)(ws + 131072 + 2 * M);
    _Float16* h16  = hbase;          // canonical activations [b][n][256]
    _Float16* hA16 = hbase + M;      // MLP1 out / hn
    _Float16* d16  = hbase + 2 * M;
    _Float16* q16  = hbase + 3 * M;  // [bh][n][64]
    _Float16* k16  = hbase + 4 * M;
    _Float16* v16  = hbase + 5 * M;  // [bh][64][n]

    dim3 g1(NB, NC / 64, NN / 32);   // (2,4,64)

    gemm_mfma<1, false, false><<<g1, 256, 0, stream>>>(in_w1, in_b1, in_g1, in_be1, x,    hA16);
    gemm_mfma<1, true,  false><<<g1, 256, 0, stream>>>(in_w2, in_b2, in_g2, in_be2, hA16, h16);

    for (int l = 0; l < NL; l++) {
        qkv_fused<<<dim3(NB * NH, NN / 64), 256, 0, stream>>>(
            q_w, k_w, v_w, v_b, h16, q16, k16, v16, l);
        rowsum_part<<<dim3(NB * NH, NN / 64, 4), 256, 0, stream>>>(q16, k16, rowsum_p);
        attn_part<<<dim3(NB * NH, NN / 64, 4), 256, 0, stream>>>(
            q16, k16, v16, rowsum_p, xrp16, csp);
        reduce_dx<<<dim3(NB * NH, NN / 32, 2), 256, 0, stream>>>(xrp16, csp, h16, d16);
        delta_mfma<<<dim3(NB * NH, NN / 32), 256, 0, stream>>>(
            t_w, t_b, bn_g, bn_b, h16, d16, hA16, l);
        if (l < NL - 1) {
            gemm_mfma<0, true, false><<<g1, 256, 0, stream>>>(
                proj_w + (size_t)l * NC * NC, proj_b + (size_t)l * NC,
                nullptr, nullptr, hA16, h16);
        } else {
            gemm_mfma<0, true, true><<<g1, 256, 0, stream>>>(
                proj_w + (size_t)l * NC * NC, proj_b + (size_t)l * NC,
                nullptr, nullptr, hA16, d_out);
        }
    }
}

// Round 15
// 433.143 us; speedup vs baseline: 1.0396x; 1.0396x over previous
//
#include <hip/hip_runtime.h>
#include <math.h>

constexpr int NB = 2, NN = 2048, NC = 256, NL = 4, NH = 4, ND = 64;
constexpr float EPSV = 1e-5f;

using half8 = __attribute__((ext_vector_type(8))) _Float16;
using half4 = __attribute__((ext_vector_type(4))) _Float16;
using f32x4 = __attribute__((ext_vector_type(4))) float;

__device__ __forceinline__ f32x4 mfma16(half8 a, half8 b, f32x4 c) {
    return __builtin_amdgcn_mfma_f32_16x16x32_f16(a, b, c, 0, 0, 0);
}
__device__ __forceinline__ half8 cvt8(const float* p) {
    float4 x0 = *(const float4*)p, x1 = *(const float4*)(p + 4);
    half8 h;
    h[0]=(_Float16)x0.x; h[1]=(_Float16)x0.y; h[2]=(_Float16)x0.z; h[3]=(_Float16)x0.w;
    h[4]=(_Float16)x1.x; h[5]=(_Float16)x1.y; h[6]=(_Float16)x1.z; h[7]=(_Float16)x1.w;
    return h;
}

// ---------------------------------------------------------------------------
// out[b][n][o] = epi( sum_k W[o][k] * in[b][n][k] ), K=NC. (validated R7-R14)
template<int EPI, bool INF16, bool OUT32>
__global__ __launch_bounds__(256) void gemm_mfma(
    const float* __restrict__ Wg, const float* __restrict__ bias,
    const float* __restrict__ gam, const float* __restrict__ bet,
    const void* __restrict__ inp, void* __restrict__ outp)
{
    int b = blockIdx.x, o0 = blockIdx.y * 64, n0 = blockIdx.z * 32;
    int t = threadIdx.x, w = t >> 6, li = t & 15, qd = (t >> 4) & 3;
    const float* wr = Wg + (size_t)(o0 + w * 16 + li) * NC + qd * 8;
    half8 af[8];
#pragma unroll
    for (int ks = 0; ks < 8; ++ks) af[ks] = cvt8(wr + ks * 32);
    f32x4 acc[2];
    acc[0] = {0.f, 0.f, 0.f, 0.f}; acc[1] = {0.f, 0.f, 0.f, 0.f};
#pragma unroll
    for (int ks = 0; ks < 8; ++ks) {
#pragma unroll
        for (int g = 0; g < 2; ++g) {
            int n = n0 + g * 16 + li;
            half8 bf;
            if (INF16) {
                bf = *(const half8*)((const _Float16*)inp +
                        ((size_t)(b * NN + n) * NC + ks * 32 + qd * 8));
            } else {
                bf = cvt8((const float*)inp + ((size_t)(b * NN + n) * NC + ks * 32 + qd * 8));
            }
            acc[g] = mfma16(af[ks], bf, acc[g]);
        }
    }
    int ob = o0 + w * 16 + qd * 4;
    float4 bs = *(const float4*)(bias + ob);
    float4 gs = {0,0,0,0}, be = {0,0,0,0};
    if (EPI == 1) { gs = *(const float4*)(gam + ob); be = *(const float4*)(bet + ob); }
    float scl = rsqrtf(1.f + EPSV);
#pragma unroll
    for (int g = 0; g < 2; ++g) {
        int n = n0 + g * 16 + li;
        float v4[4];
#pragma unroll
        for (int r = 0; r < 4; ++r) {
            float v = acc[g][r] + ((const float*)&bs)[r];
            if (EPI == 1)
                v = fmaxf(0.f, v * (((const float*)&gs)[r] * scl) + ((const float*)&be)[r]);
            v4[r] = v;
        }
        if (OUT32) {
            float4 fv = {v4[0], v4[1], v4[2], v4[3]};
            *(float4*)((float*)outp + (size_t)(b * NN + n) * NC + ob) = fv;
        } else {
            half4 hv;
#pragma unroll
            for (int r = 0; r < 4; ++r) hv[r] = (_Float16)v4[r];
            *(half4*)((_Float16*)outp + (size_t)(b * NN + n) * NC + ob) = hv;
        }
    }
}

// q/k -> [bh][n][64] ; v -> [bh][64][n] (+bias). grid (8, NN/64). (validated R8/R10)
__global__ __launch_bounds__(256) void qkv_fused(
    const float* __restrict__ qw, const float* __restrict__ kw,
    const float* __restrict__ vw, const float* __restrict__ vb,
    const _Float16* __restrict__ h16, _Float16* __restrict__ q16,
    _Float16* __restrict__ k16, _Float16* __restrict__ v16, int l)
{
    int bh = blockIdx.x, n0 = blockIdx.y * 64;
    int hh = bh & 3, b = bh >> 2;
    size_t wbase = (size_t)(l * NH + hh) * ND * ND;
    int t = threadIdx.x, w = t >> 6, li = t & 15, qd = (t >> 4) & 3;
    size_t wro = (size_t)(w * 16 + li) * ND + qd * 8;
    half8 aq0 = cvt8(qw + wbase + wro), aq1 = cvt8(qw + wbase + wro + 32);
    half8 ak0 = cvt8(kw + wbase + wro), ak1 = cvt8(kw + wbase + wro + 32);
    half8 av0 = cvt8(vw + wbase + wro), av1 = cvt8(vw + wbase + wro + 32);
    f32x4 accq[4], acck[4], accv[4];
#pragma unroll
    for (int g = 0; g < 4; ++g) {
        accq[g] = {0.f,0.f,0.f,0.f}; acck[g] = {0.f,0.f,0.f,0.f}; accv[g] = {0.f,0.f,0.f,0.f};
    }
#pragma unroll
    for (int g = 0; g < 4; ++g) {
        int n = n0 + g * 16 + li;
        const _Float16* hb = h16 + ((size_t)(b * NN + n) * NC + hh * 64 + qd * 8);
        half8 b0 = *(const half8*)(hb);
        half8 b1 = *(const half8*)(hb + 32);
        accq[g] = mfma16(aq0, b0, accq[g]); accq[g] = mfma16(aq1, b1, accq[g]);
        acck[g] = mfma16(ak0, b0, acck[g]); acck[g] = mfma16(ak1, b1, acck[g]);
        accv[g] = mfma16(av0, b0, accv[g]); accv[g] = mfma16(av1, b1, accv[g]);
    }
    int ob = w * 16 + qd * 4;
    _Float16* qo = q16 + (size_t)bh * NN * ND;
    _Float16* ko = k16 + (size_t)bh * NN * ND;
#pragma unroll
    for (int g = 0; g < 4; ++g) {
        int n = n0 + g * 16 + li;
        half4 hq, hk;
#pragma unroll
        for (int r = 0; r < 4; ++r) { hq[r] = (_Float16)accq[g][r]; hk[r] = (_Float16)acck[g][r]; }
        *(half4*)(qo + (size_t)n * ND + ob) = hq;
        *(half4*)(ko + (size_t)n * ND + ob) = hk;
    }
    float4 vb4 = *(const float4*)(vb + (size_t)(l * NH + hh) * ND + ob);
    _Float16* vo = v16 + (size_t)bh * ND * NN;
#pragma unroll
    for (int g = 0; g < 4; ++g) {
        int n = n0 + g * 16 + li;
#pragma unroll
        for (int r = 0; r < 4; ++r)
            vo[(size_t)(ob + r) * NN + n] = (_Float16)(accv[g][r] + ((const float*)&vb4)[r]);
    }
}

// rowsum partials: rowsum_p[ms][bh][n] = sum_{m in ms-range} exp(S[n,m]).
// grid (8, NN/64, 4), block 256; 8 iters each. (validated R10/R13)
__global__ __launch_bounds__(256) void rowsum_part(
    const _Float16* __restrict__ qh, const _Float16* __restrict__ kh,
    float* __restrict__ rowsum_p)
{
    int bh = blockIdx.x, nt = blockIdx.y, ms = blockIdx.z;
    const _Float16* qp = qh + (size_t)bh * NN * ND;
    const _Float16* kp = kh + (size_t)bh * NN * ND;
    int t = threadIdx.x, w = t >> 6, li = t & 15, qd = (t >> 4) & 3;
    int nr = nt * 64 + w * 16;
    half8 aq0 = *(const half8*)(qp + (size_t)(nr + li) * ND + qd * 8);
    half8 aq1 = *(const half8*)(qp + (size_t)(nr + li) * ND + qd * 8 + 32);
    float rsacc[4] = {0.f, 0.f, 0.f, 0.f};
    for (int it = 0; it < 8; ++it) {
        int m0 = ms * 512 + it * 64;
        f32x4 s[4];
#pragma unroll
        for (int g = 0; g < 4; ++g) {
            const _Float16* kb = kp + (size_t)(m0 + g * 16 + li) * ND + qd * 8;
            half8 b0 = *(const half8*)(kb);
            half8 b1 = *(const half8*)(kb + 32);
            s[g] = {0.f, 0.f, 0.f, 0.f};
            s[g] = mfma16(aq0, b0, s[g]);
            s[g] = mfma16(aq1, b1, s[g]);
        }
#pragma unroll
        for (int r = 0; r < 4; ++r)
            rsacc[r] += __expf(s[0][r]) + __expf(s[1][r]) + __expf(s[2][r]) + __expf(s[3][r]);
    }
#pragma unroll
    for (int r = 0; r < 4; ++r) {
        float v = rsacc[r];
        v += __shfl_xor(v, 1); v += __shfl_xor(v, 2);
        v += __shfl_xor(v, 4); v += __shfl_xor(v, 8);
        if (li == 0) rowsum_p[((size_t)(ms * NB * NH + bh)) * NN + nr + qd * 4 + r] = v;
    }
}

// attn partials: per (bh, m-tile 64, ns of 4): n-range 512 (8 iters).
// R13 champion: stride 72, prefetch of v(it) + q/rowsum(it+1). grid (8, 32, 4).
__global__ __launch_bounds__(256) void attn_part(
    const _Float16* __restrict__ qh, const _Float16* __restrict__ kh,
    const _Float16* __restrict__ vh, const float* __restrict__ rowsum_p,
    _Float16* __restrict__ xrp16, float* __restrict__ csp)
{
    int bh = blockIdx.x, m0 = blockIdx.y * 64, ns = blockIdx.z;
    const _Float16* qp = qh + (size_t)bh * NN * ND;
    const _Float16* kp = kh + (size_t)bh * NN * ND;
    const _Float16* vp = vh + (size_t)bh * ND * NN;
    __shared__ __align__(16) _Float16 Plds[2][64 * 72];
    __shared__ float cs_wave[4][64];
    int t = threadIdx.x, w = t >> 6, li = t & 15, qd = (t >> 4) & 3;
    const size_t RSS = (size_t)NB * NH * NN;
    half8 bk[4][2];
#pragma unroll
    for (int g = 0; g < 4; ++g) {
        const _Float16* kb = kp + (size_t)(m0 + g * 16 + li) * ND + qd * 8;
        bk[g][0] = *(const half8*)(kb);
        bk[g][1] = *(const half8*)(kb + 32);
    }
    f32x4 acc[4];
#pragma unroll
    for (int g = 0; g < 4; ++g) acc[g] = {0.f, 0.f, 0.f, 0.f};
    float csacc[4] = {0.f, 0.f, 0.f, 0.f};
    int nb0 = ns * 512;
    const _Float16* qrow0 = qp + (size_t)(nb0 + w * 16 + li) * ND + qd * 8;
    half8 aq0 = *(const half8*)(qrow0);
    half8 aq1 = *(const half8*)(qrow0 + 32);
    int ridx = bh * NN + nb0 + w * 16 + qd * 4;
    float4 r0 = *(const float4*)(rowsum_p + ridx);
    float4 r1 = *(const float4*)(rowsum_p + RSS + ridx);
    float4 r2 = *(const float4*)(rowsum_p + 2 * RSS + ridx);
    float4 r3 = *(const float4*)(rowsum_p + 3 * RSS + ridx);
    for (int it = 0; it < 8; ++it) {
        int n0 = ns * 512 + it * 64;
        _Float16* Pb = Plds[it & 1];
        const _Float16* vrow = vp + (size_t)(w * 16 + li) * NN + n0 + qd * 8;
        half8 av0 = *(const half8*)(vrow);
        half8 av1 = *(const half8*)(vrow + 32);
        f32x4 s[4];
#pragma unroll
        for (int g = 0; g < 4; ++g) {
            s[g] = {0.f, 0.f, 0.f, 0.f};
            s[g] = mfma16(aq0, bk[g][0], s[g]);
            s[g] = mfma16(aq1, bk[g][1], s[g]);
        }
        float irs[4];
        irs[0] = 1.f / (r0.x + r1.x + r2.x + r3.x);
        irs[1] = 1.f / (r0.y + r1.y + r2.y + r3.y);
        irs[2] = 1.f / (r0.z + r1.z + r2.z + r3.z);
        irs[3] = 1.f / (r0.w + r1.w + r2.w + r3.w);
        if (it < 7) {
            const _Float16* nqrow = qp + (size_t)(n0 + 64 + w * 16 + li) * ND + qd * 8;
            aq0 = *(const half8*)(nqrow);
            aq1 = *(const half8*)(nqrow + 32);
            int nridx = bh * NN + n0 + 64 + w * 16 + qd * 4;
            r0 = *(const float4*)(rowsum_p + nridx);
            r1 = *(const float4*)(rowsum_p + RSS + nridx);
            r2 = *(const float4*)(rowsum_p + 2 * RSS + nridx);
            r3 = *(const float4*)(rowsum_p + 3 * RSS + nridx);
        }
#pragma unroll
        for (int g = 0; g < 4; ++g) {
            half4 pv; float lsum = 0.f;
#pragma unroll
            for (int r = 0; r < 4; ++r) {
                float p = __expf(s[g][r]) * irs[r];
                lsum += p;
                pv[r] = (_Float16)p;
            }
            csacc[g] += lsum;
            *(half4*)(&Pb[(g * 16 + li) * 72 + w * 16 + qd * 4]) = pv;
        }
        __syncthreads();   // P_i visible; double buffer protects P_{i-1} readers
#pragma unroll
        for (int g = 0; g < 4; ++g) {
            half8 b0 = *(const half8*)(&Pb[(g * 16 + li) * 72 + qd * 8]);
            half8 b1 = *(const half8*)(&Pb[(g * 16 + li) * 72 + qd * 8 + 32]);
            acc[g] = mfma16(av0, b0, acc[g]);
            acc[g] = mfma16(av1, b1, acc[g]);
        }
    }
#pragma unroll
    for (int g = 0; g < 4; ++g) {
        float v = csacc[g];
        v += __shfl_xor(v, 16); v += __shfl_xor(v, 32);
        if (qd == 0) cs_wave[w][g * 16 + li] = v;
    }
    __syncthreads();
    if (t < 64) {
        float cs = cs_wave[0][t] + cs_wave[1][t] + cs_wave[2][t] + cs_wave[3][t];
        csp[((size_t)ns * NB * NH + bh) * NN + m0 + t] = cs;
    }
    _Float16* xo = xrp16 + (size_t)ns * ((size_t)NB * NC * NN);
#pragma unroll
    for (int g = 0; g < 4; ++g)
#pragma unroll
        for (int r = 0; r < 4; ++r)
            xo[(size_t)(bh * 64 + w * 16 + qd * 4 + r) * NN + m0 + g * 16 + li] =
                (_Float16)acc[g][r];
}

// Fused: xt[c][n] = (sum_ns xr)[c][n]/(1e-9+sum_ns cs[n]);
// d = h - xt (fp32, from LDS); t = Wt d + tb ; hn = h + relu(bn(t)).
// grid (8, NN/32), block 256. (correctness-validated in R11; NSPL=4 variant)
__global__ __launch_bounds__(256) void delta_fused(
    const float* __restrict__ tw, const float* __restrict__ tb,
    const float* __restrict__ bng, const float* __restrict__ bnb,
    const _Float16* __restrict__ xrp16, const float* __restrict__ csp,
    const _Float16* __restrict__ h16, _Float16* __restrict__ hn16, int l)
{
    int bh = blockIdx.x, n0 = blockIdx.y * 32;
    int hh = bh & 3, b = bh >> 2;
    __shared__ float xt[64][33];   // [c][n_local], normalized xr
    int t = threadIdx.x;
    {   // phase 1: sum slices, normalize, transpose-store
        int xcol = t & 31, yr = t >> 5;
        int m = n0 + xcol;
        const size_t CSS = (size_t)NB * NH * NN;
        float cs = 1e-9f;
#pragma unroll
        for (int sl = 0; sl < 4; ++sl) cs += csp[sl * CSS + (size_t)bh * NN + m];
        float icv = 1.f / cs;
        const size_t XSS = (size_t)NB * NC * NN;
#pragma unroll
        for (int r = 0; r < 8; ++r) {
            int c = yr + 8 * r;
            size_t off = (size_t)(bh * 64 + c) * NN + m;
            float s = 0.f;
#pragma unroll
            for (int sl = 0; sl < 4; ++sl) s += (float)xrp16[sl * XSS + off];
            xt[c][xcol] = s * icv;
        }
    }
    __syncthreads();
    // phase 2: delta MFMA with B = h - xt built from LDS
    int w = t >> 6, li = t & 15, qd = (t >> 4) & 3;
    const float* wp = tw + (size_t)(l * NH + hh) * ND * ND;
    const float* wr = wp + (size_t)(w * 16 + li) * ND + qd * 8;
    half8 af0 = cvt8(wr), af1 = cvt8(wr + 32);
    f32x4 acc[2];
    acc[0] = {0.f, 0.f, 0.f, 0.f}; acc[1] = {0.f, 0.f, 0.f, 0.f};
#pragma unroll
    for (int g = 0; g < 2; ++g) {
        int nl = g * 16 + li;
        size_t hoff = (size_t)(b * NN + n0 + nl) * NC + hh * 64;
        half8 h0 = *(const half8*)(h16 + hoff + qd * 8);
        half8 h1 = *(const half8*)(h16 + hoff + 32 + qd * 8);
        half8 b0, b1;
#pragma unroll
        for (int j = 0; j < 8; ++j) {
            b0[j] = (_Float16)((float)h0[j] - xt[qd * 8 + j][nl]);
            b1[j] = (_Float16)((float)h1[j] - xt[32 + qd * 8 + j][nl]);
        }
        acc[g] = mfma16(af0, b0, acc[g]);
        acc[g] = mfma16(af1, b1, acc[g]);
    }
    int ob = w * 16 + qd * 4;
    float4 tb4 = *(const float4*)(tb  + (size_t)(l * NH + hh) * ND + ob);
    float4 g4  = *(const float4*)(bng + (size_t)(l * NH + hh) * ND + ob);
    float4 b4  = *(const float4*)(bnb + (size_t)(l * NH + hh) * ND + ob);
    float scl = rsqrtf(1.f + EPSV);
#pragma unroll
    for (int g = 0; g < 2; ++g) {
        int n = n0 + g * 16 + li;
        size_t off = (size_t)(b * NN + n) * NC + hh * 64 + ob;
        half4 h4 = *(const half4*)(h16 + off);
        half4 hv;
#pragma unroll
        for (int r = 0; r < 4; ++r) {
            float tv = acc[g][r] + ((const float*)&tb4)[r];
            float x2 = fmaxf(0.f, tv * (((const float*)&g4)[r] * scl) + ((const float*)&b4)[r]);
            hv[r] = (_Float16)((float)h4[r] + x2);
        }
        *(half4*)(hn16 + off) = hv;
    }
}

extern "C" void kernel_launch(void* const* d_in, const int* in_sizes, int n_in,
                              void* d_out, int out_size, void* d_ws, size_t ws_size,
                              hipStream_t stream)
{
    (void)in_sizes; (void)n_in; (void)out_size; (void)ws_size;
    const float* x      = (const float*)d_in[0];
    const float* in_w1  = (const float*)d_in[1];
    const float* in_b1  = (const float*)d_in[2];
    const float* in_g1  = (const float*)d_in[3];
    const float* in_be1 = (const float*)d_in[4];
    const float* in_w2  = (const float*)d_in[5];
    const float* in_b2  = (const float*)d_in[6];
    const float* in_g2  = (const float*)d_in[7];
    const float* in_be2 = (const float*)d_in[8];
    const float* q_w    = (const float*)d_in[9];
    const float* k_w    = (const float*)d_in[10];
    const float* v_w    = (const float*)d_in[11];
    const float* v_b    = (const float*)d_in[12];
    const float* t_w    = (const float*)d_in[13];
    const float* t_b    = (const float*)d_in[14];
    const float* bn_g   = (const float*)d_in[15];
    const float* bn_b   = (const float*)d_in[16];
    const float* proj_w = (const float*)d_in[17];
    const float* proj_b = (const float*)d_in[18];

    float* ws = (float*)d_ws;
    const size_t M = (size_t)NB * NC * NN;             // 1,048,576
    float* rowsum_p = ws;                              // 4 x 16384 fp32
    float* csp      = ws + 65536;                      // 4 x 16384 fp32
    _Float16* xrp16 = (_Float16*)(ws + 131072);        // 4 x M halfs
    _Float16* hbase = (_Float16*)(ws + 131072 + 2 * M);
    _Float16* h16  = hbase;          // canonical activations [b][n][256]
    _Float16* hA16 = hbase + M;      // MLP1 out / hn
    _Float16* q16  = hbase + 2 * M;  // [bh][n][64]
    _Float16* k16  = hbase + 3 * M;
    _Float16* v16  = hbase + 4 * M;  // [bh][64][n]

    dim3 g1(NB, NC / 64, NN / 32);   // (2,4,64)

    gemm_mfma<1, false, false><<<g1, 256, 0, stream>>>(in_w1, in_b1, in_g1, in_be1, x,    hA16);
    gemm_mfma<1, true,  false><<<g1, 256, 0, stream>>>(in_w2, in_b2, in_g2, in_be2, hA16, h16);

    for (int l = 0; l < NL; l++) {
        qkv_fused<<<dim3(NB * NH, NN / 64), 256, 0, stream>>>(
            q_w, k_w, v_w, v_b, h16, q16, k16, v16, l);
        rowsum_part<<<dim3(NB * NH, NN / 64, 4), 256, 0, stream>>>(q16, k16, rowsum_p);
        attn_part<<<dim3(NB * NH, NN / 64, 4), 256, 0, stream>>>(
            q16, k16, v16, rowsum_p, xrp16, csp);
        delta_fused<<<dim3(NB * NH, NN / 32), 256, 0, stream>>>(
            t_w, t_b, bn_g, bn_b, xrp16, csp, h16, hA16, l);
        if (l < NL - 1) {
            gemm_mfma<0, true, false><<<g1, 256, 0, stream>>>(
                proj_w + (size_t)l * NC * NC, proj_b + (size_t)l * NC,
                nullptr, nullptr, hA16, h16);
        } else {
            gemm_mfma<0, true, true><<<g1, 256, 0, stream>>>(
                proj_w + (size_t)l * NC * NC, proj_b + (size_t)l * NC,
                nullptr, nullptr, hA16, d_out);
        }
    }
}